// Round 3
// baseline (357.243 us; speedup 1.0000x reference)
//
#include <hip/hip_runtime.h>

// DCKModule: conv1(1x1 MFMA)+BN+ReLU -> conv2(1x1 MFMA) -> 7x7 involution + residual
// B=8 C=256 H=W=96, R=64, G=16 GC=16 K=7 PAD=3
#define Bn   8
#define Cn   256
#define Hn   96
#define Wn   96
#define Rn   64
#define Gn   16
#define GCn  16
#define HWn  (Hn * Wn)          // 9216
#define BN_EPS 1e-5f

#define STRIPS   12             // strips of 8 output rows
#define SROWS    8
#define FMROWS   14             // SROWS + 6 halo rows
#define FMCOLS   56             // 48 px + 6 halo + 2 pad (px-split twin)
#define NCHUNK   3              // three 16-col chunks per twin
#define DFSTRIDE 138            // f32 df row: 128 px + 3-gap per 32 + pad
// df column map: col(px) = px + 3*(px>>5)  (injective; mixes px-row bits into
// bank parity so the 16*r_ term doesn't collapse to even banks -> ~2-way)

typedef short  short8  __attribute__((ext_vector_type(8)));
typedef float  floatx4 __attribute__((ext_vector_type(4)));
typedef float  floatx2 __attribute__((ext_vector_type(2)));

__device__ __forceinline__ unsigned short f2bf(float f) {
    unsigned u = __float_as_uint(f);
    u += 0x7FFFu + ((u >> 16) & 1u);      // round-to-nearest-even
    return (unsigned short)(u >> 16);
}
__device__ __forceinline__ float lo2f(unsigned u) { return __uint_as_float(u << 16); }
__device__ __forceinline__ float hi2f(unsigned u) { return __uint_as_float(u & 0xFFFF0000u); }

// ---------------------------------------------------------------------------
// K0: prep — w2bf (784x64 -> bf16, zero-pad to 816 rows), w1bf (64x256 bf16,
// same layout as W1 = A-operand [m=o][k=c]), folded BN constants iv/sh.
// ---------------------------------------------------------------------------
__global__ __launch_bounds__(256) void k0_prep(
    const float* __restrict__ W1, const float* __restrict__ W2,
    const float* __restrict__ gamma, const float* __restrict__ beta,
    const float* __restrict__ mean,  const float* __restrict__ var,
    unsigned short* __restrict__ w2bf, unsigned short* __restrict__ w1bf,
    float* __restrict__ ivp, float* __restrict__ shp)
{
    const int i = blockIdx.x * 256 + threadIdx.x;
    if (i < 816 * 64)
        w2bf[i] = (i < 784 * 64) ? f2bf(W2[i]) : (unsigned short)0;
    const int j = i - 816 * 64;
    if (j >= 0 && j < 64 * 256)
        w1bf[j] = f2bf(W1[j]);
    const int k = j - 64 * 256;
    if (k >= 0 && k < 64) {
        const float iv = gamma[k] * rsqrtf(var[k] + BN_EPS);
        ivp[k] = iv;
        shp[k] = beta[k] - mean[k] * iv;
    }
}

// ---------------------------------------------------------------------------
// K1: conv1 via MFMA, no LDS, no barriers. x_bf[b][px][64]. (round-0 version)
// ---------------------------------------------------------------------------
__global__ __launch_bounds__(256) void k1_conv1_mfma(
    const float* __restrict__ guide, const unsigned short* __restrict__ w1bf,
    const float* __restrict__ ivp, const float* __restrict__ shp,
    unsigned short* __restrict__ xbf)
{
    const int t    = threadIdx.x;
    const int lane = t & 63, wv = t >> 6;
    const int ln   = lane & 15, quad = lane >> 4;
    const int bx   = blockIdx.x;
    const int b    = bx / 144;
    const int px   = (bx - b * 144) * 64 + wv * 16 + ln;

    const float* gp = guide + b * (Cn * HWn) + (quad * 8) * HWn + px;

    floatx4 acc[4];
#pragma unroll
    for (int mt = 0; mt < 4; ++mt) acc[mt] = (floatx4){0.f, 0.f, 0.f, 0.f};

#pragma unroll 2
    for (int c0 = 0; c0 < Cn; c0 += 32) {
        float bv[8];
#pragma unroll
        for (int j = 0; j < 8; ++j) bv[j] = gp[(c0 + j) * HWn];
        short8 bfrag;
#pragma unroll
        for (int j = 0; j < 8; ++j) bfrag[j] = (short)f2bf(bv[j]);
#pragma unroll
        for (int mt = 0; mt < 4; ++mt) {
            const short8 af = *(const short8*)(w1bf + (mt * 16 + ln) * Cn + c0 + quad * 8);
            acc[mt] = __builtin_amdgcn_mfma_f32_16x16x32_bf16(af, bfrag, acc[mt], 0, 0, 0);
        }
    }

    unsigned short* xp = xbf + (b * HWn + px) * 64;
#pragma unroll
    for (int mt = 0; mt < 4; ++mt) {
#pragma unroll
        for (int rp = 0; rp < 2; ++rp) {
            const int o = mt * 16 + quad * 4 + rp * 2;      // C row
            const float v0 = fmaxf(fmaf(acc[mt][rp * 2],     ivp[o],     shp[o]),     0.f);
            const float v1 = fmaxf(fmaf(acc[mt][rp * 2 + 1], ivp[o + 1], shp[o + 1]), 0.f);
            *(unsigned*)(xp + o) = (unsigned)f2bf(v0) | ((unsigned)f2bf(v1) << 16);
        }
    }
}

// ---------------------------------------------------------------------------
// K3: fused conv2 (MFMA) + involution + residual. PX-split twins (48 cols,
// all 16 gc). sDF now f32 (phase A stores MFMA output directly: no f2bf, no
// 2-lane-per-dword write conflicts; phase B reads df with zero unpack).
// Phase B pair algebra uses only ALIGNED bf16 pairs P0..P3 (u0..u3 unpacked
// in place) for both px parities -> 6 pk_fma + 2 fma per (gi,di), no moves:
//   even px: (f0,f1)(f2,f3)(f4,f5)*df[0..5] + f6*df6
//   odd  px: (f2,f3)(f4,f5)(f6,f7)*df[1..6] + f1*df0
// LDS: sFM 16*14*56*2 = 25,088 + sDF 49*138*4 = 27,048 = 52,136 -> 3 blk/CU.
// ---------------------------------------------------------------------------
__global__ __launch_bounds__(256, 3) void k3_main(
    const float* __restrict__ fm, const unsigned short* __restrict__ xbf,
    const unsigned short* __restrict__ w2bf, float* __restrict__ out)
{
    __shared__ unsigned short sFM[GCn][FMROWS][FMCOLS];
    __shared__ float sDF[49][DFSTRIDE];

    int bx = blockIdx.x;
    const int half  = bx & 1;   bx >>= 1;
    const int g     = bx & 15;  bx >>= 4;
    const int strip = bx % STRIPS;
    const int b     = bx / STRIPS;
    const int row0  = strip * SROWS;
    const int t     = threadIdx.x;
    const int c0    = half * 48;                  // first output col of twin

    // ---- stage fm strip: 16 gc x 14 rows x (48 px + 6 halo) cols, bf16 ----
    {
        const float* fb = fm + (b * Cn + g * GCn) * HWn;
        for (int e = t; e < GCn * FMROWS * 14; e += 256) {
            const int q  = e % 14;
            const int rm = e / 14;
            const int ri = rm % FMROWS;
            const int gc = rm / FMROWS;
            const int gr   = row0 + ri - 3;
            const int gcol = c0 - 4 + q * 4;
            float4 v = make_float4(0.f, 0.f, 0.f, 0.f);
            if ((unsigned)gr < (unsigned)Hn && (unsigned)gcol < (unsigned)Wn)
                v = *(const float4*)(fb + gc * HWn + gr * Wn + gcol);
            const int L = q * 4 - 1;
            if (L >= 0)      sFM[gc][ri][L]     = f2bf(v.x);
            if (L + 1 <= 54) sFM[gc][ri][L + 1] = f2bf(v.y);
            if (L + 2 <= 54) sFM[gc][ri][L + 2] = f2bf(v.z);
            if (L + 3 <= 54) sFM[gc][ri][L + 3] = f2bf(v.w);
        }
    }

    const int lane = t & 63, wv = t >> 6;
    const int ln   = lane & 15, quad = lane >> 4;

    // W2 A-frags: held in registers across all chunks
    short8 af[4][2];
    {
        const unsigned short* wb = w2bf + (g * 49 + ln) * 64 + quad * 8;
#pragma unroll
        for (int mt = 0; mt < 4; ++mt) {
            af[mt][0] = *(const short8*)(wb + mt * 16 * 64);
            af[mt][1] = *(const short8*)(wb + mt * 16 * 64 + 32);
        }
    }

    const int r_  = lane >> 3;                    // phase-B row 0..7
    const int pr  = lane & 7;                     // phase-B col-pair 0..7
    const int pxe = r_ * 16 + 2 * pr;             // chunk-local even px
    const int ce  = pxe + 3 * (pxe >> 5);         // df column (even px)
    const float* pe = &sDF[0][ce];                // odd px = pe[... + 1]

#pragma unroll 1
    for (int ch = 0; ch < NCHUNK; ++ch) {
        const int cb = ch * 16;

        // ---- phase A: df for this chunk via MFMA, stored f32 ----
#pragma unroll
        for (int jj = 0; jj < 2; ++jj) {
            const int nt = wv * 2 + jj;                 // strip-local row
            const unsigned short* xp =
                xbf + ((b * HWn + (row0 + nt) * Wn + c0 + cb + ln) * 64 + quad * 8);
            const short8 b0 = *(const short8*)xp;
            const short8 b1 = *(const short8*)(xp + 32);
            const int px   = nt * 16 + ln;
            const int colp = px + 3 * (nt >> 1);        // px>>5 == nt>>1
#pragma unroll
            for (int mt = 0; mt < 4; ++mt) {
                floatx4 acc = {0.f, 0.f, 0.f, 0.f};
                acc = __builtin_amdgcn_mfma_f32_16x16x32_bf16(af[mt][0], b0, acc, 0, 0, 0);
                acc = __builtin_amdgcn_mfma_f32_16x16x32_bf16(af[mt][1], b1, acc, 0, 0, 0);
#pragma unroll
                for (int rr = 0; rr < 4; ++rr) {
                    const int m = mt * 16 + quad * 4 + rr;
                    float v = acc[rr];
                    if (m == 24) v += 1.0f;             // residual -> center tap
                    if (m < 49) sDF[m][colp] = v;
                }
            }
        }
        __syncthreads();

        // ---- phase B: involution for this chunk (4 gc x px-pair / thread) ----
        {
            floatx2 aE[4], aO[4];
            float   sE[4], sO[4];
#pragma unroll
            for (int gi = 0; gi < 4; ++gi) {
                aE[gi] = (floatx2){0.f, 0.f};
                aO[gi] = (floatx2){0.f, 0.f};
                sE[gi] = 0.f; sO[gi] = 0.f;
            }

#pragma unroll
            for (int di = 0; di < 7; ++di) {
                // df taps, f32, zero unpack (immediate-offset ds_read_b32)
                const float de0 = pe[(di * 7 + 0) * DFSTRIDE];
                const float de1 = pe[(di * 7 + 1) * DFSTRIDE];
                const float de2 = pe[(di * 7 + 2) * DFSTRIDE];
                const float de3 = pe[(di * 7 + 3) * DFSTRIDE];
                const float de4 = pe[(di * 7 + 4) * DFSTRIDE];
                const float de5 = pe[(di * 7 + 5) * DFSTRIDE];
                const float de6 = pe[(di * 7 + 6) * DFSTRIDE];
                const float do0 = pe[(di * 7 + 0) * DFSTRIDE + 1];
                const float do1 = pe[(di * 7 + 1) * DFSTRIDE + 1];
                const float do2 = pe[(di * 7 + 2) * DFSTRIDE + 1];
                const float do3 = pe[(di * 7 + 3) * DFSTRIDE + 1];
                const float do4 = pe[(di * 7 + 4) * DFSTRIDE + 1];
                const float do5 = pe[(di * 7 + 5) * DFSTRIDE + 1];
                const float do6 = pe[(di * 7 + 6) * DFSTRIDE + 1];
                const floatx2 E0 = {de0, de1}, E1 = {de2, de3}, E2 = {de4, de5};
                const floatx2 O0 = {do1, do2}, O1 = {do3, do4}, O2 = {do5, do6};
#pragma unroll
                for (int gi = 0; gi < 4; ++gi) {
                    const int gc = wv * 4 + gi;
                    const unsigned* fp = (const unsigned*)&sFM[gc][r_ + di][cb + 2 * pr];
                    const unsigned u0 = fp[0], u1 = fp[1], u2 = fp[2], u3 = fp[3];
                    const floatx2 P0 = {lo2f(u0), hi2f(u0)};
                    const floatx2 P1 = {lo2f(u1), hi2f(u1)};
                    const floatx2 P2 = {lo2f(u2), hi2f(u2)};
                    const floatx2 P3 = {lo2f(u3), hi2f(u3)};
                    aE[gi] += P0 * E0;
                    aE[gi] += P1 * E1;
                    aE[gi] += P2 * E2;
                    sE[gi] = fmaf(P3[0], de6, sE[gi]);
                    aO[gi] += P1 * O0;
                    aO[gi] += P2 * O1;
                    aO[gi] += P3 * O2;
                    sO[gi] = fmaf(P0[1], do0, sO[gi]);
                }
            }
#pragma unroll
            for (int gi = 0; gi < 4; ++gi) {
                const int gc = wv * 4 + gi;
                const floatx2 o2 = {aE[gi][0] + aE[gi][1] + sE[gi],
                                    aO[gi][0] + aO[gi][1] + sO[gi]};
                float* op = out + ((b * Cn + g * GCn + gc) * Hn + row0 + r_) * Wn
                            + c0 + cb + 2 * pr;
                __builtin_nontemporal_store(o2, (floatx2*)op);
            }
        }
        __syncthreads();
    }
}

// ---------------------------------------------------------------------------
extern "C" void kernel_launch(void* const* d_in, const int* in_sizes, int n_in,
                              void* d_out, int out_size, void* d_ws, size_t ws_size,
                              hipStream_t stream)
{
    const float* fm    = (const float*)d_in[0];
    const float* guide = (const float*)d_in[1];
    const float* W1    = (const float*)d_in[2];
    const float* gamma = (const float*)d_in[3];
    const float* beta  = (const float*)d_in[4];
    const float* mean  = (const float*)d_in[5];
    const float* var   = (const float*)d_in[6];
    const float* W2    = (const float*)d_in[7];
    float* out = (float*)d_out;

    // ws: xbf [8][9216][64] u16 (9,437,184 B) | w2bf [816][64] u16 (104,448 B)
    //     | w1bf [64][256] u16 (32,768 B) | iv [64] f32 | sh [64] f32
    char* wsb = (char*)d_ws;
    unsigned short* xbf  = (unsigned short*)wsb;
    unsigned short* w2bf = (unsigned short*)(wsb + 9437184);
    unsigned short* w1bf = (unsigned short*)(wsb + 9437184 + 104448);
    float*          ivp  = (float*)(wsb + 9437184 + 104448 + 32768);
    float*          shp  = ivp + 64;

    k0_prep<<<269, 256, 0, stream>>>(W1, W2, gamma, beta, mean, var,
                                     w2bf, w1bf, ivp, shp);
    k1_conv1_mfma<<<Bn * 144, 256, 0, stream>>>(guide, w1bf, ivp, shp, xbf);
    k3_main<<<Bn * STRIPS * Gn * 2, 256, 0, stream>>>(fm, xbf, w2bf, out);
}

// Round 4
// 286.636 us; speedup vs baseline: 1.2463x; 1.2463x over previous
//
#include <hip/hip_runtime.h>

// DCKModule: conv1(1x1 MFMA)+BN+ReLU -> conv2(1x1 MFMA) -> 7x7 involution + residual
// B=8 C=256 H=W=96, R=64, G=16 GC=16 K=7 PAD=3
#define Bn   8
#define Cn   256
#define Hn   96
#define Wn   96
#define Rn   64
#define Gn   16
#define GCn  16
#define HWn  (Hn * Wn)          // 9216
#define BN_EPS 1e-5f

#define STRIPS   12             // strips of 8 output rows
#define SROWS    8
#define FMROWS   14             // SROWS + 6 halo rows
#define FMCOLS   56             // 48 px + 6 halo + 2 pad (px-split twin)
#define NCHUNK   3              // three 16-col chunks per twin
#define DFSTRIDE 130            // f32 df row stride: 128 px + 2 pad
// 130 dwords == 8 banks shift per +4 rows -> phase-A stores land 2/bank
// (free); phase-B reads are wave-uniform-row -> conflict-free.

typedef short  short8  __attribute__((ext_vector_type(8)));
typedef float  floatx4 __attribute__((ext_vector_type(4)));
typedef float  floatx2 __attribute__((ext_vector_type(2)));

__device__ __forceinline__ unsigned short f2bf(float f) {
    unsigned u = __float_as_uint(f);
    u += 0x7FFFu + ((u >> 16) & 1u);      // round-to-nearest-even
    return (unsigned short)(u >> 16);
}
__device__ __forceinline__ float lo2f(unsigned u) { return __uint_as_float(u << 16); }
__device__ __forceinline__ float hi2f(unsigned u) { return __uint_as_float(u & 0xFFFF0000u); }

// ---------------------------------------------------------------------------
// K0: prep — w2bf (784x64 -> bf16, zero-pad to 816 rows), w1bf (64x256 bf16,
// same layout as W1 = A-operand [m=o][k=c]), folded BN constants iv/sh.
// ---------------------------------------------------------------------------
__global__ __launch_bounds__(256) void k0_prep(
    const float* __restrict__ W1, const float* __restrict__ W2,
    const float* __restrict__ gamma, const float* __restrict__ beta,
    const float* __restrict__ mean,  const float* __restrict__ var,
    unsigned short* __restrict__ w2bf, unsigned short* __restrict__ w1bf,
    float* __restrict__ ivp, float* __restrict__ shp)
{
    const int i = blockIdx.x * 256 + threadIdx.x;
    if (i < 816 * 64)
        w2bf[i] = (i < 784 * 64) ? f2bf(W2[i]) : (unsigned short)0;
    const int j = i - 816 * 64;
    if (j >= 0 && j < 64 * 256)
        w1bf[j] = f2bf(W1[j]);
    const int k = j - 64 * 256;
    if (k >= 0 && k < 64) {
        const float iv = gamma[k] * rsqrtf(var[k] + BN_EPS);
        ivp[k] = iv;
        shp[k] = beta[k] - mean[k] * iv;
    }
}

// ---------------------------------------------------------------------------
// K1: conv1 via MFMA, no LDS, no barriers. x_bf[b][px][64]. (round-0 version)
// ---------------------------------------------------------------------------
__global__ __launch_bounds__(256) void k1_conv1_mfma(
    const float* __restrict__ guide, const unsigned short* __restrict__ w1bf,
    const float* __restrict__ ivp, const float* __restrict__ shp,
    unsigned short* __restrict__ xbf)
{
    const int t    = threadIdx.x;
    const int lane = t & 63, wv = t >> 6;
    const int ln   = lane & 15, quad = lane >> 4;
    const int bx   = blockIdx.x;
    const int b    = bx / 144;
    const int px   = (bx - b * 144) * 64 + wv * 16 + ln;

    const float* gp = guide + b * (Cn * HWn) + (quad * 8) * HWn + px;

    floatx4 acc[4];
#pragma unroll
    for (int mt = 0; mt < 4; ++mt) acc[mt] = (floatx4){0.f, 0.f, 0.f, 0.f};

#pragma unroll 2
    for (int c0 = 0; c0 < Cn; c0 += 32) {
        float bv[8];
#pragma unroll
        for (int j = 0; j < 8; ++j) bv[j] = gp[(c0 + j) * HWn];
        short8 bfrag;
#pragma unroll
        for (int j = 0; j < 8; ++j) bfrag[j] = (short)f2bf(bv[j]);
#pragma unroll
        for (int mt = 0; mt < 4; ++mt) {
            const short8 af = *(const short8*)(w1bf + (mt * 16 + ln) * Cn + c0 + quad * 8);
            acc[mt] = __builtin_amdgcn_mfma_f32_16x16x32_bf16(af, bfrag, acc[mt], 0, 0, 0);
        }
    }

    unsigned short* xp = xbf + (b * HWn + px) * 64;
#pragma unroll
    for (int mt = 0; mt < 4; ++mt) {
#pragma unroll
        for (int rp = 0; rp < 2; ++rp) {
            const int o = mt * 16 + quad * 4 + rp * 2;      // C row
            const float v0 = fmaxf(fmaf(acc[mt][rp * 2],     ivp[o],     shp[o]),     0.f);
            const float v1 = fmaxf(fmaf(acc[mt][rp * 2 + 1], ivp[o + 1], shp[o + 1]), 0.f);
            *(unsigned*)(xp + o) = (unsigned)f2bf(v0) | ((unsigned)f2bf(v1) << 16);
        }
    }
}

// ---------------------------------------------------------------------------
// K3: fused conv2 (MFMA) + involution + residual. PX-split twins (48 cols,
// all 16 gc). Identical structure to the 113.5us round-2 kernel; the ONLY
// change is sDF bf16 -> f32: phase A stores MFMA output directly (no f2bf,
// conflict-free b32 writes at stride 130), phase B reads the {even,odd} df
// pair with one aligned ds_read_b64 (zero unpack; same dfv[7] floatx2 shape).
// LDS: sFM 16*14*56*2 = 25,088 + sDF 49*130*4 = 25,480 = 50,568 -> 3 blk/CU.
// ---------------------------------------------------------------------------
__global__ __launch_bounds__(256, 3) void k3_main(
    const float* __restrict__ fm, const unsigned short* __restrict__ xbf,
    const unsigned short* __restrict__ w2bf, float* __restrict__ out)
{
    __shared__ unsigned short sFM[GCn][FMROWS][FMCOLS];
    __shared__ float sDF[49][DFSTRIDE];

    int bx = blockIdx.x;
    const int half  = bx & 1;   bx >>= 1;
    const int g     = bx & 15;  bx >>= 4;
    const int strip = bx % STRIPS;
    const int b     = bx / STRIPS;
    const int row0  = strip * SROWS;
    const int t     = threadIdx.x;
    const int c0    = half * 48;                  // first output col of twin

    // ---- stage fm strip: 16 gc x 14 rows x (48 px + 6 halo) cols, bf16 ----
    {
        const float* fb = fm + (b * Cn + g * GCn) * HWn;
        for (int e = t; e < GCn * FMROWS * 14; e += 256) {
            const int q  = e % 14;
            const int rm = e / 14;
            const int ri = rm % FMROWS;
            const int gc = rm / FMROWS;
            const int gr   = row0 + ri - 3;
            const int gcol = c0 - 4 + q * 4;
            float4 v = make_float4(0.f, 0.f, 0.f, 0.f);
            if ((unsigned)gr < (unsigned)Hn && (unsigned)gcol < (unsigned)Wn)
                v = *(const float4*)(fb + gc * HWn + gr * Wn + gcol);
            const int L = q * 4 - 1;
            if (L >= 0)      sFM[gc][ri][L]     = f2bf(v.x);
            if (L + 1 <= 54) sFM[gc][ri][L + 1] = f2bf(v.y);
            if (L + 2 <= 54) sFM[gc][ri][L + 2] = f2bf(v.z);
            if (L + 3 <= 54) sFM[gc][ri][L + 3] = f2bf(v.w);
        }
    }

    const int lane = t & 63, wv = t >> 6;
    const int ln   = lane & 15, quad = lane >> 4;

    // W2 A-frags: held in registers across all chunks
    short8 af[4][2];
    {
        const unsigned short* wb = w2bf + (g * 49 + ln) * 64 + quad * 8;
#pragma unroll
        for (int mt = 0; mt < 4; ++mt) {
            af[mt][0] = *(const short8*)(wb + mt * 16 * 64);
            af[mt][1] = *(const short8*)(wb + mt * 16 * 64 + 32);
        }
    }

    const int r_  = lane >> 3;                    // phase-B row 0..7
    const int pr  = lane & 7;                     // phase-B col-pair 0..7
    const int pxe = r_ * 16 + 2 * pr;             // chunk-local even px (=2*lane%128)

#pragma unroll 1
    for (int ch = 0; ch < NCHUNK; ++ch) {
        const int cb = ch * 16;

        // ---- phase A: df for this chunk via MFMA, stored f32 ----
#pragma unroll
        for (int jj = 0; jj < 2; ++jj) {
            const int nt = wv * 2 + jj;                 // strip-local row
            const unsigned short* xp =
                xbf + ((b * HWn + (row0 + nt) * Wn + c0 + cb + ln) * 64 + quad * 8);
            const short8 b0 = *(const short8*)xp;
            const short8 b1 = *(const short8*)(xp + 32);
            const int px = nt * 16 + ln;
#pragma unroll
            for (int mt = 0; mt < 4; ++mt) {
                floatx4 acc = {0.f, 0.f, 0.f, 0.f};
                acc = __builtin_amdgcn_mfma_f32_16x16x32_bf16(af[mt][0], b0, acc, 0, 0, 0);
                acc = __builtin_amdgcn_mfma_f32_16x16x32_bf16(af[mt][1], b1, acc, 0, 0, 0);
#pragma unroll
                for (int rr = 0; rr < 4; ++rr) {
                    const int m = mt * 16 + quad * 4 + rr;
                    float v = acc[rr];
                    if (m == 24) v += 1.0f;             // residual -> center tap
                    if (m < 49) sDF[m][px] = v;
                }
            }
        }
        __syncthreads();

        // ---- phase B: involution for this chunk (4 gc x px-pair / thread) ----
        {
            floatx2 acc2[4];
#pragma unroll
            for (int gi = 0; gi < 4; ++gi) acc2[gi] = (floatx2){0.f, 0.f};

#pragma unroll
            for (int di = 0; di < 7; ++di) {
                floatx2 dfv[7];
#pragma unroll
                for (int dj = 0; dj < 7; ++dj)          // one ds_read_b64 each
                    dfv[dj] = *(const floatx2*)&sDF[di * 7 + dj][pxe];
#pragma unroll
                for (int gi = 0; gi < 4; ++gi) {
                    const int gc = wv * 4 + gi;
                    const unsigned* fp = (const unsigned*)&sFM[gc][r_ + di][cb + 2 * pr];
                    const unsigned u0 = fp[0], u1 = fp[1], u2 = fp[2], u3 = fp[3];
                    const float f[8] = {lo2f(u0), hi2f(u0), lo2f(u1), hi2f(u1),
                                        lo2f(u2), hi2f(u2), lo2f(u3), hi2f(u3)};
#pragma unroll
                    for (int dj = 0; dj < 7; ++dj) {
                        const floatx2 fv = (floatx2){f[dj], f[dj + 1]};
                        acc2[gi] += fv * dfv[dj];
                    }
                }
            }
#pragma unroll
            for (int gi = 0; gi < 4; ++gi) {
                const int gc = wv * 4 + gi;
                float* op = out + ((b * Cn + g * GCn + gc) * Hn + row0 + r_) * Wn
                            + c0 + cb + 2 * pr;
                __builtin_nontemporal_store(acc2[gi], (floatx2*)op);
            }
        }
        __syncthreads();
    }
}

// ---------------------------------------------------------------------------
extern "C" void kernel_launch(void* const* d_in, const int* in_sizes, int n_in,
                              void* d_out, int out_size, void* d_ws, size_t ws_size,
                              hipStream_t stream)
{
    const float* fm    = (const float*)d_in[0];
    const float* guide = (const float*)d_in[1];
    const float* W1    = (const float*)d_in[2];
    const float* gamma = (const float*)d_in[3];
    const float* beta  = (const float*)d_in[4];
    const float* mean  = (const float*)d_in[5];
    const float* var   = (const float*)d_in[6];
    const float* W2    = (const float*)d_in[7];
    float* out = (float*)d_out;

    // ws: xbf [8][9216][64] u16 (9,437,184 B) | w2bf [816][64] u16 (104,448 B)
    //     | w1bf [64][256] u16 (32,768 B) | iv [64] f32 | sh [64] f32
    char* wsb = (char*)d_ws;
    unsigned short* xbf  = (unsigned short*)wsb;
    unsigned short* w2bf = (unsigned short*)(wsb + 9437184);
    unsigned short* w1bf = (unsigned short*)(wsb + 9437184 + 104448);
    float*          ivp  = (float*)(wsb + 9437184 + 104448 + 32768);
    float*          shp  = ivp + 64;

    k0_prep<<<269, 256, 0, stream>>>(W1, W2, gamma, beta, mean, var,
                                     w2bf, w1bf, ivp, shp);
    k1_conv1_mfma<<<Bn * 144, 256, 0, stream>>>(guide, w1bf, ivp, shp, xbf);
    k3_main<<<Bn * STRIPS * Gn * 2, 256, 0, stream>>>(fm, xbf, w2bf, out);
}